// Round 1
// baseline (374.652 us; speedup 1.0000x reference)
//
#include <hip/hip_runtime.h>
#include <hip/hip_bf16.h>

#define RS 0.9999950000374998f  // 1/sqrt(1+1e-5)

__device__ __forceinline__ float eluf(float x) {
    return x > 0.0f ? x : expf(x) - 1.0f;
}

// ---------------------------------------------------------------------------
// Generic tiled f32 GEMM: out[r, c] = post(sum_k A[r,k] * W[k,c] + bias[c])
// post: ACT -> elu; BN -> *gamma/sqrt(1+eps) + beta
// rows multiple of 64, Ncols multiple of 64, Kdim multiple of 16.
// block 256, grid (rows/64, Ncols/64)
// ---------------------------------------------------------------------------
template <int ACT, int BN>
__global__ __launch_bounds__(256) void gemm_bias_act(
    const float* __restrict__ A, const float* __restrict__ W,
    const float* __restrict__ bias, const float* __restrict__ gamma,
    const float* __restrict__ beta, float* __restrict__ out,
    int Kdim, int Ncols) {
    __shared__ float As[16][64];
    __shared__ float Bs[16][64];
    const int tid = threadIdx.x;
    const int tx = tid & 15, ty = tid >> 4;
    const long row0 = (long)blockIdx.x * 64;
    const int col0 = blockIdx.y * 64;
    const int rA = tid >> 2, kqA = (tid & 3) << 2;
    const int kkB = tid >> 4, cqB = (tid & 15) << 2;
    float acc[4][4] = {};
    for (int k0 = 0; k0 < Kdim; k0 += 16) {
        const float4 av = *reinterpret_cast<const float4*>(
            A + (row0 + rA) * (long)Kdim + (k0 + kqA));
        const float4 bv = *reinterpret_cast<const float4*>(
            W + (long)(k0 + kkB) * Ncols + (col0 + cqB));
        As[kqA + 0][rA] = av.x;
        As[kqA + 1][rA] = av.y;
        As[kqA + 2][rA] = av.z;
        As[kqA + 3][rA] = av.w;
        *reinterpret_cast<float4*>(&Bs[kkB][cqB]) = bv;
        __syncthreads();
#pragma unroll
        for (int kk = 0; kk < 16; ++kk) {
            float a[4], b[4];
#pragma unroll
            for (int i = 0; i < 4; ++i) a[i] = As[kk][ty * 4 + i];
#pragma unroll
            for (int j = 0; j < 4; ++j) b[j] = Bs[kk][tx * 4 + j];
#pragma unroll
            for (int i = 0; i < 4; ++i)
#pragma unroll
                for (int j = 0; j < 4; ++j) acc[i][j] = fmaf(a[i], b[j], acc[i][j]);
        }
        __syncthreads();
    }
#pragma unroll
    for (int j = 0; j < 4; ++j) {
        const int col = col0 + tx * 4 + j;
        const float bb = bias[col];
        const float gs = BN ? gamma[col] * RS : 0.0f;
        const float bt = BN ? beta[col] : 0.0f;
#pragma unroll
        for (int i = 0; i < 4; ++i) {
            const long row = row0 + ty * 4 + i;
            float v = acc[i][j] + bb;
            if (ACT) v = eluf(v);
            if (BN) v = v * gs + bt;
            out[row * Ncols + col] = v;
        }
    }
}

// ---------------------------------------------------------------------------
// Setup: per point, gather neighbor coords, compute pts_local (store) and
// Xc[gp, o] = elu(sum_{d,k} pts_local[k,d] * xt_cW[o,d,k] + cb[o])  (store)
// 16 points per block, 256 threads. grid = 32768/16 = 2048.
// ---------------------------------------------------------------------------
__global__ __launch_bounds__(256) void setup_kernel(
    const float* __restrict__ rep_pts, const float* __restrict__ pts,
    const int* __restrict__ pts_idx, const float* __restrict__ xt_cW,
    const float* __restrict__ xt_cb, float* __restrict__ pts_local,
    float* __restrict__ Xc) {
    __shared__ float cwT[48][256];  // cwT[d*16+k][o] = xt_cW[o,d,k]
    __shared__ float pl2[16][48];   // pl2[pt][d*16+k]
    __shared__ float cb_s[256];
    const int tid = threadIdx.x;
    const long gp0 = (long)blockIdx.x * 16;
#pragma unroll
    for (int i = 0; i < 48; ++i) cwT[i][tid] = xt_cW[tid * 48 + i];
    cb_s[tid] = xt_cb[tid];
    {
        const int pt = tid >> 4, k = tid & 15;
        const long gp = gp0 + pt;
        const int n = (int)(gp >> 11);
        const int idx = pts_idx[gp * 32 + 2 * k];
        const float* ps = pts + ((long)n * 8192 + idx) * 3;
        const float* rs = rep_pts + gp * 3;
        float* plo = pts_local + gp * 48 + k * 3;
#pragma unroll
        for (int d = 0; d < 3; ++d) {
            const float v = ps[d] - rs[d];
            pl2[pt][d * 16 + k] = v;
            plo[d] = v;
        }
    }
    __syncthreads();
    const int o = tid;
    for (int pt = 0; pt < 16; ++pt) {
        float acc = cb_s[o];
#pragma unroll
        for (int i = 0; i < 48; ++i) acc = fmaf(pl2[pt][i], cwT[i][o], acc);
        Xc[(gp0 + pt) * 256 + o] = eluf(acc);
    }
}

// ---------------------------------------------------------------------------
// Final per-point stage: recompute lifted, gather fts_reg, fts_X, dw.
// 4 points per block, 256 threads. grid = 32768/4 = 8192.
// Writes dw (+dw_b) [32768][192]; pw GEMM done afterwards.
// ---------------------------------------------------------------------------
__global__ __launch_bounds__(256) void final_stage_kernel(
    const float* __restrict__ X2,         // [32768][256]
    const float* __restrict__ pts_local,  // [32768][48] (k*3+d)
    const int* __restrict__ pts_idx,
    const float* __restrict__ fts_l,  // [16*8192][64]
    const float* __restrict__ d1_W, const float* __restrict__ d1_b,
    const float* __restrict__ d1_g, const float* __restrict__ d1_bt,
    const float* __restrict__ d2_W, const float* __restrict__ d2_b,
    const float* __restrict__ d2_g, const float* __restrict__ d2_bt,
    const float* __restrict__ dw_W, const float* __restrict__ dw_b,
    float* __restrict__ dw_out)  // [32768][192]
{
    __shared__ float X_s[4][256];
    __shared__ float fcat[4][16][96];  // [pt][k][c]: c<32 lifted, c>=32 fts_reg
    __shared__ float fX[4][16][96];
    __shared__ float l0_s[4][16][32];
    __shared__ float pl_s[4][48];
    __shared__ int idx_s[4][16];
    const int tid = threadIdx.x;
    const long gp0 = (long)blockIdx.x * 4;

    if (tid < 64) {
        const int pt = tid >> 4, k = tid & 15;
        idx_s[pt][k] = pts_idx[(gp0 + pt) * 32 + 2 * k];
    }
    if (tid < 192) {
        const int pt = tid / 48, e = tid - pt * 48;
        pl_s[pt][e] = pts_local[(gp0 + pt) * 48 + e];
    }
    {
        const int pt = tid >> 6, o4 = (tid & 63) * 4;
        *reinterpret_cast<float4*>(&X_s[pt][o4]) =
            *reinterpret_cast<const float4*>(&X2[(gp0 + pt) * 256 + o4]);
    }
    __syncthreads();

    // gather fts_reg -> fcat[..][32..95]
    {
        const int row = tid >> 2, q = tid & 3;
        const int pt = row >> 4, k = row & 15;
        const long gp = gp0 + pt;
        const int n = (int)(gp >> 11);
        const float* src = fts_l + ((long)n * 8192 + idx_s[pt][k]) * 64;
#pragma unroll
        for (int j = 0; j < 4; ++j) {
            const int f = q * 4 + j;
            const float4 v = *reinterpret_cast<const float4*>(src + f * 4);
            fcat[pt][k][32 + f * 4 + 0] = v.x;
            fcat[pt][k][32 + f * 4 + 1] = v.y;
            fcat[pt][k][32 + f * 4 + 2] = v.z;
            fcat[pt][k][32 + f * 4 + 3] = v.w;
        }
    }
    // l0 = bn(elu(pts_local @ d1_W + b))
#pragma unroll
    for (int s = 0; s < 8; ++s) {
        const int oid = s * 256 + tid;
        const int c = oid & 31, kk = (oid >> 5) & 15, pt = oid >> 9;
        float acc = d1_b[c];
#pragma unroll
        for (int d = 0; d < 3; ++d)
            acc = fmaf(pl_s[pt][kk * 3 + d], d1_W[d * 32 + c], acc);
        acc = eluf(acc);
        l0_s[pt][kk][c] = acc * (d1_g[c] * RS) + d1_bt[c];
    }
    __syncthreads();
    // lifted = bn(elu(l0 @ d2_W + b)) -> fcat[..][0..31]
#pragma unroll
    for (int s = 0; s < 8; ++s) {
        const int oid = s * 256 + tid;
        const int c = oid & 31, kk = (oid >> 5) & 15, pt = oid >> 9;
        float acc = d2_b[c];
#pragma unroll
        for (int j = 0; j < 32; ++j)
            acc = fmaf(l0_s[pt][kk][j], d2_W[j * 32 + c], acc);
        acc = eluf(acc);
        fcat[pt][kk][c] = acc * (d2_g[c] * RS) + d2_bt[c];
    }
    __syncthreads();
    // fts_X[pt][i][c] = sum_j X[pt][i*16+j] * fcat[pt][j][c]
    {
        const int pt = tid >> 6, lane = tid & 63;
        for (int rep = 0; rep < 24; ++rep) {
            const int ol = rep * 64 + lane;  // 0..1535
            const int i = ol / 96;
            const int c = ol - i * 96;
            float acc = 0.0f;
#pragma unroll
            for (int j = 0; j < 16; ++j)
                acc = fmaf(X_s[pt][i * 16 + j], fcat[pt][j][c], acc);
            fX[pt][i][c] = acc;
        }
    }
    __syncthreads();
    // dw[pt][c*2+m] = sum_k fX[pt][k][c] * dw_W[c,m,k] + dw_b
#pragma unroll
    for (int s = 0; s < 3; ++s) {
        const int oid = s * 256 + tid;
        const int pt = oid / 192;
        const int r = oid - pt * 192;
        const int c = r >> 1, m = r & 1;
        float acc = dw_b[r];
#pragma unroll
        for (int k = 0; k < 16; ++k)
            acc = fmaf(fX[pt][k][c], dw_W[c * 32 + m * 16 + k], acc);
        dw_out[(gp0 + pt) * 192 + r] = acc;
    }
}

extern "C" void kernel_launch(void* const* d_in, const int* in_sizes, int n_in,
                              void* d_out, int out_size, void* d_ws,
                              size_t ws_size, hipStream_t stream) {
    const float* rep_pts = (const float*)d_in[0];
    const float* pts = (const float*)d_in[1];
    const float* fts = (const float*)d_in[2];
    const int* pts_idx = (const int*)d_in[3];
    const float* dense_W = (const float*)d_in[4];
    const float* dense_b = (const float*)d_in[5];
    const float* dense_g = (const float*)d_in[6];
    const float* dense_bt = (const float*)d_in[7];
    const float* d1_W = (const float*)d_in[8];
    const float* d1_b = (const float*)d_in[9];
    const float* d1_g = (const float*)d_in[10];
    const float* d1_bt = (const float*)d_in[11];
    const float* d2_W = (const float*)d_in[12];
    const float* d2_b = (const float*)d_in[13];
    const float* d2_g = (const float*)d_in[14];
    const float* d2_bt = (const float*)d_in[15];
    const float* xt_cW = (const float*)d_in[16];
    const float* xt_cb = (const float*)d_in[17];
    const float* xt_d1W = (const float*)d_in[18];
    const float* xt_d1b = (const float*)d_in[19];
    const float* xt_d2W = (const float*)d_in[20];
    const float* xt_d2b = (const float*)d_in[21];
    const float* dw_W = (const float*)d_in[22];
    const float* dw_b = (const float*)d_in[23];
    const float* pw_W = (const float*)d_in[24];
    const float* pw_b = (const float*)d_in[25];
    const float* sep_g = (const float*)d_in[26];
    const float* sep_bt = (const float*)d_in[27];

    float* ws = (float*)d_ws;
    float* fts_l = ws;               // 131072*64  = 8388608 f32
    float* bufA = ws + 8388608;      // Xc then X2 : 32768*256
    float* bufB = ws + 16777216;     // X1 then dw : 32768*256
    float* pl = ws + 25165824;       // 32768*48

    // 1) fts_l = bn(elu(fts @ dense_W + b))   (131072 x 64) @ (64 x 64)
    gemm_bias_act<1, 1><<<dim3(2048, 1), 256, 0, stream>>>(
        fts, dense_W, dense_b, dense_g, dense_bt, fts_l, 64, 64);

    // 2) pts_local + Xc
    setup_kernel<<<2048, 256, 0, stream>>>(rep_pts, pts, pts_idx, xt_cW, xt_cb,
                                           pl, bufA);

    // 3) X1 = elu(Xc @ xt_d1W + b)   (32768 x 256) @ (256 x 256)
    gemm_bias_act<1, 0><<<dim3(512, 4), 256, 0, stream>>>(
        bufA, xt_d1W, xt_d1b, nullptr, nullptr, bufB, 256, 256);

    // 4) X2 = X1 @ xt_d2W + b
    gemm_bias_act<0, 0><<<dim3(512, 4), 256, 0, stream>>>(
        bufB, xt_d2W, xt_d2b, nullptr, nullptr, bufA, 256, 256);

    // 5) lifted/gather/fts_X/dw -> bufB [32768][192]
    final_stage_kernel<<<8192, 256, 0, stream>>>(
        bufA, pl, pts_idx, fts_l, d1_W, d1_b, d1_g, d1_bt, d2_W, d2_b, d2_g,
        d2_bt, dw_W, dw_b, bufB);

    // 6) out = bn(elu(dw @ pw_W + pw_b))   (32768 x 192) @ (192 x 128)
    gemm_bias_act<1, 1><<<dim3(512, 2), 256, 0, stream>>>(
        bufB, pw_W, pw_b, sep_g, sep_bt, (float*)d_out, 192, 128);
}